// Round 1
// 2885.551 us; speedup vs baseline: 1.0938x; 1.0938x over previous
//
#include <hip/hip_runtime.h>

#define CN0 50000
#define CE0 200000
#define CN1 100000
#define CE1 400000

// ---------------- fill ----------------
__global__ void fill_k(float* __restrict__ p, float v, int n) {
    int i = blockIdx.x * 256 + threadIdx.x;
    if (i < n) p[i] = v;
}

// ---------------- GEMM: Y[N,M] = X[N,K] @ W[K,M] (+bias[M]) (+add[N,M]) ----------------
// 128x128 tile, BK=16, 256 threads, 8x8 register tile per thread. fp32.
// Requires: M % 128 == 0, K % 16 == 0 (all call sites satisfy: M in {128,256}, K in {64,128,256}).
// Ws columns are XOR-swizzled (c ^ ((c>>3)&12)) so the tx*8-stride b128 reads are 2-way (free)
// instead of 4-way bank-aliased.
__global__ __launch_bounds__(256) void gemm_k(
        const float* __restrict__ X, const float* __restrict__ W,
        const float* __restrict__ bias, const float* __restrict__ add,
        float* __restrict__ Y, int N, int K, int M) {
    __shared__ float Xs[16][132];   // [k][row]
    __shared__ float Ws[16][132];   // [k][col_swizzled]
    const int bm = blockIdx.y * 128;
    const int bn = blockIdx.x * 128;
    const int tid = threadIdx.x;
    const int tx = tid & 15, ty = tid >> 4;       // col group / row group
    // staging indices
    const int xr = tid >> 2;                      // 0..63 (row within tile; +64 on pass 2)
    const int xc = (tid & 3) * 4;                 // k offset (float4)
    const int wr = tid >> 5;                      // 0..7  (k row; +8 on pass 2)
    const int wc = (tid & 31) * 4;                // col offset (float4)
    const int wcs = wc ^ ((wc >> 3) & 12);        // swizzled store col
    // hoisted read bases
    const int xb = ty * 8;
    const int c0 = tx * 8,          c1 = tx * 8 + 4;
    const int p0 = c0 ^ ((c0 >> 3) & 12), p1 = c1 ^ ((c1 >> 3) & 12);

    float acc[8][8] = {};
    for (int k0 = 0; k0 < K; k0 += 16) {
        // load X tile: 128 rows x 16 k, transposed into Xs[k][row]
        #pragma unroll
        for (int p = 0; p < 2; ++p) {
            int r = xr + p * 64;
            int gr = bm + r;
            float4 v = make_float4(0.f, 0.f, 0.f, 0.f);
            if (gr < N) v = *(const float4*)&X[(long)gr * K + k0 + xc];
            Xs[xc + 0][r] = v.x;
            Xs[xc + 1][r] = v.y;
            Xs[xc + 2][r] = v.z;
            Xs[xc + 3][r] = v.w;
        }
        // load W tile: 16 k x 128 cols (swizzled float4 store)
        #pragma unroll
        for (int p = 0; p < 2; ++p) {
            int r = wr + p * 8;
            float4 v = *(const float4*)&W[(long)(k0 + r) * M + bn + wc];
            *(float4*)&Ws[r][wcs] = v;
        }
        __syncthreads();
        #pragma unroll
        for (int k = 0; k < 16; ++k) {
            float xv[8], wv[8];
            #pragma unroll
            for (int i = 0; i < 8; ++i) xv[i] = Xs[k][xb + i];
            float4 wa = *(const float4*)&Ws[k][p0];
            float4 wb = *(const float4*)&Ws[k][p1];
            wv[0] = wa.x; wv[1] = wa.y; wv[2] = wa.z; wv[3] = wa.w;
            wv[4] = wb.x; wv[5] = wb.y; wv[6] = wb.z; wv[7] = wb.w;
            #pragma unroll
            for (int i = 0; i < 8; ++i)
                #pragma unroll
                for (int j = 0; j < 8; ++j) acc[i][j] += xv[i] * wv[j];
        }
        __syncthreads();
    }
    const int row0 = bm + ty * 8;
    const int col0 = bn + tx * 8;
    float4 b0 = make_float4(0.f, 0.f, 0.f, 0.f), b1 = b0;
    if (bias) {
        b0 = *(const float4*)&bias[col0];
        b1 = *(const float4*)&bias[col0 + 4];
    }
    #pragma unroll
    for (int i = 0; i < 8; ++i) {
        int gr = row0 + i;
        if (gr >= N) continue;
        float4 v0, v1;
        v0.x = acc[i][0] + b0.x; v0.y = acc[i][1] + b0.y;
        v0.z = acc[i][2] + b0.z; v0.w = acc[i][3] + b0.w;
        v1.x = acc[i][4] + b1.x; v1.y = acc[i][5] + b1.y;
        v1.z = acc[i][6] + b1.z; v1.w = acc[i][7] + b1.w;
        if (add) {
            float4 a0 = *(const float4*)&add[(long)gr * M + col0];
            float4 a1 = *(const float4*)&add[(long)gr * M + col0 + 4];
            v0.x += a0.x; v0.y += a0.y; v0.z += a0.z; v0.w += a0.w;
            v1.x += a1.x; v1.y += a1.y; v1.z += a1.z; v1.w += a1.w;
        }
        *(float4*)&Y[(long)gr * M + col0]     = v0;
        *(float4*)&Y[(long)gr * M + col0 + 4] = v1;
    }
}

// ---------------- edge kernel: f = lrelu(FNi[src]+FNj[dst]+FEb[e>>sh]); ef_out = sum_h f; logits = f . attn ----------------
// one wave (64 lanes) per edge, H=2 fixed
__global__ __launch_bounds__(256) void edge_k(
        const float* __restrict__ FNi, const float* __restrict__ FNj,
        const float* __restrict__ FEb, const float* __restrict__ attn,
        const int* __restrict__ src, const int* __restrict__ dst,
        int E, int out_e, int fe_shift,
        float* __restrict__ ef_out, float* __restrict__ logits) {
    int e = blockIdx.x * 4 + (threadIdx.x >> 6);
    int lane = threadIdx.x & 63;
    if (e >= E) return;
    int s = src[e], d = dst[e];
    long fi = (long)s * (2 * out_e);
    long fj = (long)d * (2 * out_e);
    long fe = (long)(e >> fe_shift) * (2 * out_e);
    float l0 = 0.f, l1 = 0.f;
    for (int c = lane; c < out_e; c += 64) {
        float f0 = FNi[fi + c] + FNj[fj + c] + FEb[fe + c];
        f0 = f0 > 0.f ? f0 : 0.01f * f0;
        float f1 = FNi[fi + out_e + c] + FNj[fj + out_e + c] + FEb[fe + out_e + c];
        f1 = f1 > 0.f ? f1 : 0.01f * f1;
        l0 += f0 * attn[c];
        l1 += f1 * attn[out_e + c];
        ef_out[(long)e * out_e + c] = f0 + f1;
    }
    #pragma unroll
    for (int off = 32; off > 0; off >>= 1) {
        l0 += __shfl_down(l0, off);
        l1 += __shfl_down(l1, off);
    }
    if (lane == 0) { logits[2 * e] = l0; logits[2 * e + 1] = l1; }
}

// ---------------- segment max via atomic int/uint trick ----------------
__device__ __forceinline__ void atomicMaxF(float* addr, float v) {
    if (v >= 0.f) atomicMax((int*)addr, __float_as_int(v));
    else          atomicMin((unsigned int*)addr, __float_as_uint(v));
}

__global__ void segmax_k(const float* __restrict__ logits, const int* __restrict__ dst,
                         int E, float* __restrict__ emax) {
    int i = blockIdx.x * 256 + threadIdx.x;
    if (i >= E) return;
    int d = dst[i];
    atomicMaxF(&emax[2 * d],     logits[2 * i]);
    atomicMaxF(&emax[2 * d + 1], logits[2 * i + 1]);
}

// ---------------- ee = exp(logit - emax[dst]); denom[dst] += ee ----------------
__global__ void eednm_k(const float* __restrict__ logits, const int* __restrict__ dst,
                        int E, const float* __restrict__ emax,
                        float* __restrict__ ee, float* __restrict__ denom) {
    int i = blockIdx.x * 256 + threadIdx.x;
    if (i >= E) return;
    int d = dst[i];
    float e0 = expf(logits[2 * i]     - emax[2 * d]);
    float e1 = expf(logits[2 * i + 1] - emax[2 * d + 1]);
    ee[2 * i] = e0; ee[2 * i + 1] = e1;
    atomicAdd(&denom[2 * d],     e0);
    atomicAdd(&denom[2 * d + 1], e1);
}

// ---------------- scatter: out[dst] += a0*Hn[src][0,:] + a1*Hn[src][1,:]  (out_n=128, Hn stride 256) ----------------
__global__ __launch_bounds__(256) void scatter_k(
        const float* __restrict__ Hn, const float* __restrict__ ee,
        const float* __restrict__ denom, const int* __restrict__ src,
        const int* __restrict__ dst, int E, float* __restrict__ out) {
    int e = blockIdx.x * 4 + (threadIdx.x >> 6);
    int lane = threadIdx.x & 63;
    if (e >= E) return;
    int s = src[e], d = dst[e];
    float a0 = ee[2 * e]     / denom[2 * d];
    float a1 = ee[2 * e + 1] / denom[2 * d + 1];
    const float* h = Hn + (long)s * 256;
    float* o = out + (long)d * 128;
    #pragma unroll
    for (int c = lane; c < 128; c += 64)
        atomicAdd(&o[c], a0 * h[c] + a1 * h[128 + c]);
}

extern "C" void kernel_launch(void* const* d_in, const int* in_sizes, int n_in,
                              void* d_out, int out_size, void* d_ws, size_t ws_size,
                              hipStream_t stream) {
    const float* node_feats   = (const float*)d_in[0];
    const float* edge_feats   = (const float*)d_in[1];
    const float* node_path_in = (const float*)d_in[2];
    const float* edge_path_in = (const float*)d_in[3];
    const float* lin1_W = (const float*)d_in[32];
    const float* lin1_b = (const float*)d_in[33];
    const int* src0 = (const int*)d_in[34];
    const int* dst0 = (const int*)d_in[35];
    const int* src1 = (const int*)d_in[36];
    const int* dst1 = (const int*)d_in[37];

    float* out  = (float*)d_out;
    float* seg0 = out;              // nf        [50000,128]  (also holds nf1 mid-flight)
    float* seg1 = out + 6400000;    // ef2       [200000,128] (also holds ef1 mid-flight)
    float* seg2 = out + 32000000;   // node_path [100000,128] (also holds np1 mid-flight)
    float* seg3 = out + 44800000;   // edge_path [400000,64]

    float* ws     = (float*)d_ws;
    float* FNi    = ws;                   // 12.8M floats
    float* FNj    = FNi + 12800000;       // 12.8M
    float* Hn     = FNj + 12800000;       // 25.6M
    float* FE     = Hn  + 25600000;       // 51.2M
    float* EF     = FE  + 51200000;       // 25.6M (edge_path intermediate from stage 2a)
    float* np2    = EF  + 25600000;       // 12.8M
    float* logits = np2 + 12800000;       // 0.8M
    float* ee     = logits + 800000;      // 0.8M
    float* emax   = ee + 800000;          // 0.2M
    float* denom  = emax + 200000;        // 0.2M
    // total ~141M floats = ~563 MB of ws

    auto gemm = [&](const float* X, const float* W, const float* b, const float* add,
                    float* Y, int N, int K, int M) {
        dim3 g(M / 128, (N + 127) / 128);
        gemm_k<<<g, 256, 0, stream>>>(X, W, b, add, Y, N, K, M);
    };
    auto fill = [&](float* p, float v, int n) {
        fill_k<<<(n + 255) / 256, 256, 0, stream>>>(p, v, n);
    };
    // One EGAT layer. base = index of <pre>_ni in d_in.
    auto egat = [&](const float* nfeats, int N, int in_n,
                    const float* efeats, int fij_rows, int in_e,
                    int out_e, int fe_shift, int base,
                    const int* src, const int* dst, int E,
                    float* ef_out, float* h_out) {
        const float* Wni   = (const float*)d_in[base + 0];
        const float* Wnj   = (const float*)d_in[base + 1];
        const float* Wfij  = (const float*)d_in[base + 2];
        const float* Wnode = (const float*)d_in[base + 3];
        const float* bnode = (const float*)d_in[base + 4];
        const float* attn  = (const float*)d_in[base + 5];
        const float* bias  = (const float*)d_in[base + 6];
        gemm(nfeats, Wni,   nullptr, nullptr, FNi, N, in_n, 2 * out_e);
        gemm(nfeats, Wnj,   nullptr, nullptr, FNj, N, in_n, 2 * out_e);
        gemm(nfeats, Wnode, bnode,   nullptr, Hn,  N, in_n, 256);
        gemm(efeats, Wfij,  bias,    nullptr, FE,  fij_rows, in_e, 2 * out_e);
        fill(emax, -3.0e38f, 2 * N);
        fill(denom, 0.f, 2 * N);
        edge_k<<<(E + 3) / 4, 256, 0, stream>>>(FNi, FNj, FE, attn, src, dst,
                                                E, out_e, fe_shift, ef_out, logits);
        segmax_k<<<(E + 255) / 256, 256, 0, stream>>>(logits, dst, E, emax);
        eednm_k<<<(E + 255) / 256, 256, 0, stream>>>(logits, dst, E, emax, ee, denom);
        fill(h_out, 0.f, N * 128);
        scatter_k<<<(E + 3) / 4, 256, 0, stream>>>(Hn, ee, denom, src, dst, E, h_out);
    };

    // ---- Stage 1: EGAT on atom graph ----  nf1 -> seg0, ef1 -> seg1
    egat(node_feats, CN0, 128, edge_feats, CE0, 128, 128, 0, 4, src0, dst0, CE0, seg1, seg0);

    // ---- Lift: x11 = ef1 viewed as [100000,256]; np1 = x11@lin1_W + lin1_b + node_path_in -> seg2
    gemm(seg1, lin1_W, lin1_b, node_path_in, seg2, CN1, 256, 128);

    // ---- Stage 2a: path graph ----  ef -> EF (ws), h -> np2 (ws)
    egat(seg2, CN1, 128, edge_path_in, CE1, 64, 64, 0, 11, src1, dst1, CE1, EF, np2);

    // ---- Stage 2b: path graph ----  ef -> seg3 (final edge_path), h -> seg2 (final node_path)
    egat(np2, CN1, 128, EF, CE1, 64, 64, 0, 18, src1, dst1, CE1, seg3, seg2);

    // ---- Stage 3: atom graph ----
    // efeats = repeat(node_path,2): fij GEMM on the 100000 unique rows, edge kernel indexes e>>1.
    // nfeats = nf1 (seg0); GEMMs consume seg0 before fill(h_out=seg0) zeroes it (same-stream order).
    egat(seg0, CN0, 128, seg2, CN1, 128, 128, 1, 25, src0, dst0, CE0, seg1, seg0);
}

// Round 2
// 2798.555 us; speedup vs baseline: 1.1278x; 1.0311x over previous
//
#include <hip/hip_runtime.h>

#define CN0 50000
#define CE0 200000
#define CN1 100000
#define CE1 400000

typedef __attribute__((ext_vector_type(8))) _Float16 half8;
typedef __attribute__((ext_vector_type(4))) _Float16 half4;
typedef __attribute__((ext_vector_type(4))) float floatx4;

// ---------------- fill ----------------
__global__ void fill_k(float* __restrict__ p, float v, int n) {
    int i = blockIdx.x * 256 + threadIdx.x;
    if (i < n) p[i] = v;
}

// ---------------- weight convert+transpose: T[m*K+k] = (f16)W[k*M+m] ----------------
struct WtDesc { const float* W; _Float16* T; int KM; int mshift; int K; };
struct WtArgs { WtDesc d[17]; };

__global__ __launch_bounds__(256) void wcvt_k(WtArgs a) {
    WtDesc w = a.d[blockIdx.y];
    const int M1 = (1 << w.mshift) - 1;
    for (int i = blockIdx.x * 256 + threadIdx.x; i < w.KM; i += 256 * gridDim.x) {
        int k = i >> w.mshift, m = i & M1;
        w.T[(long)m * w.K + k] = (_Float16)w.W[i];
    }
}

// ---------------- GEMM: Y[N,M] = X[N,K] @ W[K,M] (+bias[M]) (+add[N,M]) ----------------
// MFMA f16 inputs, fp32 accumulate. 128x128 tile, BK=64, 256 threads = 2x2 waves,
// each wave owns a 64x64 sub-tile = 4x4 fragments of 16x16x32.
// A staged in LDS as f16 [128 rows][64 k], XOR-swizzled (byte ^= (row&7)<<4) so the
// 128B row stride is conflict-free for both ds_write_b64 staging and ds_read_b128 frags.
// B read directly from pre-transposed f16 Wt[M][K] (tiny, L2-resident) — no B tile in LDS.
// Requires: M % 128 == 0, K % 64 == 0 (call sites: M in {128,256}, K in {64,128,256}).
__global__ __launch_bounds__(256) void gemm_k(
        const float* __restrict__ X, const _Float16* __restrict__ Wt,
        const float* __restrict__ bias, const float* __restrict__ add,
        float* __restrict__ Y, int N, int K, int M) {
    __shared__ _Float16 As[128 * 64];   // 16 KB
    char* asb = (char*)As;
    const int tid = threadIdx.x;
    const int lane = tid & 63;
    const int wid = tid >> 6;
    const int wr = wid >> 1, wc = wid & 1;   // wave grid 2x2
    const int bm = blockIdx.y * 128;
    const int bn = blockIdx.x * 128;
    const int l15 = lane & 15, lk = lane >> 4;

    floatx4 acc[4][4] = {};   // [row-frag][col-frag]

    for (int k0 = 0; k0 < K; k0 += 64) {
        // ---- stage A tile: 128 rows x 64 k, f32 -> f16, swizzled ----
        #pragma unroll
        for (int i = 0; i < 8; ++i) {
            int f = tid + i * 256;         // float4 slot 0..2047
            int r = f >> 4, kq = f & 15;   // row, k-quad
            int gr = bm + r;
            float4 v = make_float4(0.f, 0.f, 0.f, 0.f);
            if (gr < N) v = *(const float4*)&X[(long)gr * K + k0 + kq * 4];
            half4 hv = { (_Float16)v.x, (_Float16)v.y, (_Float16)v.z, (_Float16)v.w };
            int byte = (r * 128 + kq * 8) ^ ((r & 7) << 4);
            *(half4*)(asb + byte) = hv;
        }
        // ---- B fragments from global (independent of LDS; overlaps barrier) ----
        half8 bf[2][4];
        #pragma unroll
        for (int kk = 0; kk < 2; ++kk)
            #pragma unroll
            for (int ct = 0; ct < 4; ++ct) {
                int col = bn + wc * 64 + ct * 16 + l15;
                bf[kk][ct] = *(const half8*)&Wt[(long)col * K + k0 + kk * 32 + lk * 8];
            }
        __syncthreads();
        // ---- MFMA ----
        #pragma unroll
        for (int kk = 0; kk < 2; ++kk) {
            half8 af[4];
            #pragma unroll
            for (int rt = 0; rt < 4; ++rt) {
                int row = wr * 64 + rt * 16 + l15;
                int byte = (row * 128 + (kk * 32 + lk * 8) * 2) ^ ((row & 7) << 4);
                af[rt] = *(const half8*)(asb + byte);
            }
            #pragma unroll
            for (int rt = 0; rt < 4; ++rt)
                #pragma unroll
                for (int ct = 0; ct < 4; ++ct)
                    acc[rt][ct] = __builtin_amdgcn_mfma_f32_16x16x32_f16(
                        af[rt], bf[kk][ct], acc[rt][ct], 0, 0, 0);
        }
        __syncthreads();
    }
    // ---- epilogue: C/D frag layout col=lane&15, row=(lane>>4)*4+reg ----
    #pragma unroll
    for (int ct = 0; ct < 4; ++ct) {
        int col = bn + wc * 64 + ct * 16 + l15;
        float bv = bias ? bias[col] : 0.f;
        #pragma unroll
        for (int rt = 0; rt < 4; ++rt) {
            #pragma unroll
            for (int r = 0; r < 4; ++r) {
                int row = bm + wr * 64 + rt * 16 + lk * 4 + r;
                if (row < N) {
                    float v = acc[rt][ct][r] + bv;
                    long off = (long)row * M + col;
                    if (add) v += add[off];
                    Y[off] = v;
                }
            }
        }
    }
}

// ---------------- edge kernel: f = lrelu(FNi[src]+FNj[dst]+FEb[e>>sh]); ef_out = sum_h f; logits = f . attn ----------------
// one wave (64 lanes) per edge, H=2 fixed
__global__ __launch_bounds__(256) void edge_k(
        const float* __restrict__ FNi, const float* __restrict__ FNj,
        const float* __restrict__ FEb, const float* __restrict__ attn,
        const int* __restrict__ src, const int* __restrict__ dst,
        int E, int out_e, int fe_shift,
        float* __restrict__ ef_out, float* __restrict__ logits) {
    int e = blockIdx.x * 4 + (threadIdx.x >> 6);
    int lane = threadIdx.x & 63;
    if (e >= E) return;
    int s = src[e], d = dst[e];
    long fi = (long)s * (2 * out_e);
    long fj = (long)d * (2 * out_e);
    long fe = (long)(e >> fe_shift) * (2 * out_e);
    float l0 = 0.f, l1 = 0.f;
    for (int c = lane; c < out_e; c += 64) {
        float f0 = FNi[fi + c] + FNj[fj + c] + FEb[fe + c];
        f0 = f0 > 0.f ? f0 : 0.01f * f0;
        float f1 = FNi[fi + out_e + c] + FNj[fj + out_e + c] + FEb[fe + out_e + c];
        f1 = f1 > 0.f ? f1 : 0.01f * f1;
        l0 += f0 * attn[c];
        l1 += f1 * attn[out_e + c];
        ef_out[(long)e * out_e + c] = f0 + f1;
    }
    #pragma unroll
    for (int off = 32; off > 0; off >>= 1) {
        l0 += __shfl_down(l0, off);
        l1 += __shfl_down(l1, off);
    }
    if (lane == 0) { logits[2 * e] = l0; logits[2 * e + 1] = l1; }
}

// ---------------- segment max via atomic int/uint trick ----------------
__device__ __forceinline__ void atomicMaxF(float* addr, float v) {
    if (v >= 0.f) atomicMax((int*)addr, __float_as_int(v));
    else          atomicMin((unsigned int*)addr, __float_as_uint(v));
}

__global__ void segmax_k(const float* __restrict__ logits, const int* __restrict__ dst,
                         int E, float* __restrict__ emax) {
    int i = blockIdx.x * 256 + threadIdx.x;
    if (i >= E) return;
    int d = dst[i];
    atomicMaxF(&emax[2 * d],     logits[2 * i]);
    atomicMaxF(&emax[2 * d + 1], logits[2 * i + 1]);
}

// ---------------- ee = exp(logit - emax[dst]); denom[dst] += ee ----------------
__global__ void eednm_k(const float* __restrict__ logits, const int* __restrict__ dst,
                        int E, const float* __restrict__ emax,
                        float* __restrict__ ee, float* __restrict__ denom) {
    int i = blockIdx.x * 256 + threadIdx.x;
    if (i >= E) return;
    int d = dst[i];
    float e0 = expf(logits[2 * i]     - emax[2 * d]);
    float e1 = expf(logits[2 * i + 1] - emax[2 * d + 1]);
    ee[2 * i] = e0; ee[2 * i + 1] = e1;
    atomicAdd(&denom[2 * d],     e0);
    atomicAdd(&denom[2 * d + 1], e1);
}

// ---------------- scatter: out[dst] += a0*Hn[src][0,:] + a1*Hn[src][1,:]  (out_n=128, Hn stride 256) ----------------
__global__ __launch_bounds__(256) void scatter_k(
        const float* __restrict__ Hn, const float* __restrict__ ee,
        const float* __restrict__ denom, const int* __restrict__ src,
        const int* __restrict__ dst, int E, float* __restrict__ out) {
    int e = blockIdx.x * 4 + (threadIdx.x >> 6);
    int lane = threadIdx.x & 63;
    if (e >= E) return;
    int s = src[e], d = dst[e];
    float a0 = ee[2 * e]     / denom[2 * d];
    float a1 = ee[2 * e + 1] / denom[2 * d + 1];
    const float* h = Hn + (long)s * 256;
    float* o = out + (long)d * 128;
    #pragma unroll
    for (int c = lane; c < 128; c += 64)
        atomicAdd(&o[c], a0 * h[c] + a1 * h[128 + c]);
}

extern "C" void kernel_launch(void* const* d_in, const int* in_sizes, int n_in,
                              void* d_out, int out_size, void* d_ws, size_t ws_size,
                              hipStream_t stream) {
    const float* node_feats   = (const float*)d_in[0];
    const float* edge_feats   = (const float*)d_in[1];
    const float* node_path_in = (const float*)d_in[2];
    const float* edge_path_in = (const float*)d_in[3];
    const float* lin1_b = (const float*)d_in[33];
    const int* src0 = (const int*)d_in[34];
    const int* dst0 = (const int*)d_in[35];
    const int* src1 = (const int*)d_in[36];
    const int* dst1 = (const int*)d_in[37];

    float* out  = (float*)d_out;
    float* seg0 = out;              // nf        [50000,128]  (also holds nf1 mid-flight)
    float* seg1 = out + 6400000;    // ef2       [200000,128] (also holds ef1 mid-flight)
    float* seg2 = out + 32000000;   // node_path [100000,128] (also holds np1 mid-flight)
    float* seg3 = out + 44800000;   // edge_path [400000,64]

    float* ws     = (float*)d_ws;
    float* FNi    = ws;                   // 12.8M floats
    float* FNj    = FNi + 12800000;       // 12.8M
    float* Hn     = FNj + 12800000;       // 25.6M
    float* FE     = Hn  + 25600000;       // 51.2M
    float* EF     = FE  + 51200000;       // 25.6M (edge_path intermediate from stage 2a)
    float* np2    = EF  + 25600000;       // 12.8M
    float* logits = np2 + 12800000;       // 0.8M
    float* ee     = logits + 800000;      // 0.8M
    float* emax   = ee + 800000;          // 0.2M
    float* denom  = emax + 200000;        // 0.2M
    _Float16* WT  = (_Float16*)(denom + 200000);   // 442368 f16 = ~0.9 MB

    // ---- f16 transposed weights: index table ----
    // (d_in idx, K, M): see WtArgs below
    static const int wi_din[17]  = {4,5,6,7, 11,12,13,14, 18,19,20,21, 25,26,27,28, 32};
    static const int wi_K[17]    = {128,128,128,128, 128,128,64,128, 128,128,64,128, 128,128,128,128, 256};
    static const int wi_M[17]    = {256,256,256,256, 128,128,128,256, 128,128,128,256, 256,256,256,256, 128};
    _Float16* wt[17];
    {
        _Float16* p = WT;
        for (int i = 0; i < 17; ++i) { wt[i] = p; p += (size_t)wi_K[i] * wi_M[i]; }
    }
    {
        WtArgs a;
        for (int i = 0; i < 17; ++i) {
            a.d[i].W = (const float*)d_in[wi_din[i]];
            a.d[i].T = wt[i];
            a.d[i].KM = wi_K[i] * wi_M[i];
            a.d[i].mshift = (wi_M[i] == 256) ? 8 : 7;
            a.d[i].K = wi_K[i];
        }
        wcvt_k<<<dim3(4, 17), 256, 0, stream>>>(a);
    }

    auto gemm = [&](const float* X, const _Float16* Wt, const float* b, const float* add,
                    float* Y, int N, int K, int M) {
        dim3 g(M / 128, (N + 127) / 128);
        gemm_k<<<g, 256, 0, stream>>>(X, Wt, b, add, Y, N, K, M);
    };
    auto fill = [&](float* p, float v, int n) {
        fill_k<<<(n + 255) / 256, 256, 0, stream>>>(p, v, n);
    };
    // One EGAT layer. base = index of <pre>_ni in d_in (for bnode/attn/bias); wb = index into wt[].
    auto egat = [&](const float* nfeats, int N, int in_n,
                    const float* efeats, int fij_rows, int in_e,
                    int out_e, int fe_shift, int base, int wb,
                    const int* src, const int* dst, int E,
                    float* ef_out, float* h_out) {
        const float* bnode = (const float*)d_in[base + 4];
        const float* attn  = (const float*)d_in[base + 5];
        const float* bias  = (const float*)d_in[base + 6];
        gemm(nfeats, wt[wb + 0], nullptr, nullptr, FNi, N, in_n, 2 * out_e);
        gemm(nfeats, wt[wb + 1], nullptr, nullptr, FNj, N, in_n, 2 * out_e);
        gemm(nfeats, wt[wb + 3], bnode,   nullptr, Hn,  N, in_n, 256);
        gemm(efeats, wt[wb + 2], bias,    nullptr, FE,  fij_rows, in_e, 2 * out_e);
        fill(emax, -3.0e38f, 2 * N);
        fill(denom, 0.f, 2 * N);
        edge_k<<<(E + 3) / 4, 256, 0, stream>>>(FNi, FNj, FE, attn, src, dst,
                                                E, out_e, fe_shift, ef_out, logits);
        segmax_k<<<(E + 255) / 256, 256, 0, stream>>>(logits, dst, E, emax);
        eednm_k<<<(E + 255) / 256, 256, 0, stream>>>(logits, dst, E, emax, ee, denom);
        fill(h_out, 0.f, N * 128);
        scatter_k<<<(E + 3) / 4, 256, 0, stream>>>(Hn, ee, denom, src, dst, E, h_out);
    };

    // ---- Stage 1: EGAT on atom graph ----  nf1 -> seg0, ef1 -> seg1
    egat(node_feats, CN0, 128, edge_feats, CE0, 128, 128, 0, 4, 0, src0, dst0, CE0, seg1, seg0);

    // ---- Lift: x11 = ef1 viewed as [100000,256]; np1 = x11@lin1_W + lin1_b + node_path_in -> seg2
    gemm(seg1, wt[16], lin1_b, node_path_in, seg2, CN1, 256, 128);

    // ---- Stage 2a: path graph ----  ef -> EF (ws), h -> np2 (ws)
    egat(seg2, CN1, 128, edge_path_in, CE1, 64, 64, 0, 11, 4, src1, dst1, CE1, EF, np2);

    // ---- Stage 2b: path graph ----  ef -> seg3 (final edge_path), h -> seg2 (final node_path)
    egat(np2, CN1, 128, EF, CE1, 64, 64, 0, 18, 8, src1, dst1, CE1, seg3, seg2);

    // ---- Stage 3: atom graph ----
    // efeats = repeat(node_path,2): fij GEMM on the 100000 unique rows, edge kernel indexes e>>1.
    // nfeats = nf1 (seg0); GEMMs consume seg0 before fill(h_out=seg0) zeroes it (same-stream order).
    egat(seg0, CN0, 128, seg2, CN1, 128, 128, 1, 25, 12, src0, dst0, CE0, seg1, seg0);
}

// Round 3
// 2656.061 us; speedup vs baseline: 1.1883x; 1.0536x over previous
//
#include <hip/hip_runtime.h>

#define CN0 50000
#define CE0 200000
#define CN1 100000
#define CE1 400000

typedef __attribute__((ext_vector_type(8))) _Float16 half8;
typedef __attribute__((ext_vector_type(4))) _Float16 half4;
typedef __attribute__((ext_vector_type(4))) float floatx4;

// ---------------- fill ----------------
__global__ void fill_k(float* __restrict__ p, float v, int n) {
    int i = blockIdx.x * 256 + threadIdx.x;
    if (i < n) p[i] = v;
}

// ---------------- weight convert+transpose: T[m*K+k] = (f16)W[k*M+m] ----------------
struct WtDesc { const float* W; _Float16* T; int KM; int mshift; int K; };
struct WtArgs { WtDesc d[17]; };

__global__ __launch_bounds__(256) void wcvt_k(WtArgs a) {
    WtDesc w = a.d[blockIdx.y];
    const int M1 = (1 << w.mshift) - 1;
    for (int i = blockIdx.x * 256 + threadIdx.x; i < w.KM; i += 256 * gridDim.x) {
        int k = i >> w.mshift, m = i & M1;
        w.T[(long)m * w.K + k] = (_Float16)w.W[i];
    }
}

// ---------------- CSR build: histogram -> block scan -> carry scan -> apply -> fill ----------------
__global__ void hist2_k(const int* __restrict__ dst0, const int* __restrict__ dst1,
                        int* __restrict__ deg0, int* __restrict__ deg1) {
    int i = blockIdx.x * 256 + threadIdx.x;
    if (i < CE0) atomicAdd(&deg0[dst0[i]], 1);
    if (i < CE1) atomicAdd(&deg1[dst1[i]], 1);
}

// per-block exclusive scan of deg -> off (block-local), block totals -> bsum
__global__ __launch_bounds__(256) void scanA_k(const int* __restrict__ deg, int N,
                                               int* __restrict__ off, int* __restrict__ bsum) {
    __shared__ int s[256];
    int t = threadIdx.x, i = blockIdx.x * 256 + t;
    int v = (i < N) ? deg[i] : 0;
    s[t] = v; __syncthreads();
    #pragma unroll
    for (int d = 1; d < 256; d <<= 1) {
        int x = (t >= d) ? s[t - d] : 0;
        __syncthreads(); s[t] += x; __syncthreads();
    }
    if (i < N) off[i] = s[t] - v;
    if (t == 255) bsum[blockIdx.x] = s[255];
}

// exclusive scan of bsum arrays (block 0 -> graph0, block 1 -> graph1)
__global__ __launch_bounds__(256) void scanB_k(int* __restrict__ bsum0, int nb0,
                                               int* __restrict__ bsum1, int nb1) {
    int* bs = blockIdx.x ? bsum1 : bsum0;
    int nb  = blockIdx.x ? nb1 : nb0;
    __shared__ int s[256];
    __shared__ int tot, carry;
    int t = threadIdx.x;
    if (t == 0) carry = 0;
    __syncthreads();
    for (int base = 0; base < nb; base += 256) {
        int i = base + t;
        int v = (i < nb) ? bs[i] : 0;
        s[t] = v; __syncthreads();
        #pragma unroll
        for (int d = 1; d < 256; d <<= 1) {
            int x = (t >= d) ? s[t - d] : 0;
            __syncthreads(); s[t] += x; __syncthreads();
        }
        if (i < nb) bs[i] = s[t] - v + carry;
        if (t == 255) tot = s[255];
        __syncthreads();
        if (t == 0) carry += tot;
        __syncthreads();
    }
}

__global__ void scanC_k(int* __restrict__ off, const int* __restrict__ bsum, int N, int E) {
    int i = blockIdx.x * 256 + threadIdx.x;
    if (i < N) off[i] += bsum[i >> 8];
    if (i == 0) off[N] = E;
}

__global__ void csrfill2_k(const int* __restrict__ dst0, const int* __restrict__ off0,
                           int* __restrict__ cur0, int* __restrict__ eidx0,
                           const int* __restrict__ dst1, const int* __restrict__ off1,
                           int* __restrict__ cur1, int* __restrict__ eidx1) {
    int i = blockIdx.x * 256 + threadIdx.x;
    if (i < CE0) {
        int d = dst0[i];
        int s = atomicAdd(&cur0[d], 1);
        eidx0[off0[d] + s] = i;
    }
    if (i < CE1) {
        int d = dst1[i];
        int s = atomicAdd(&cur1[d], 1);
        eidx1[off1[d] + s] = i;
    }
}

// ---------------- GEMM: Y[N,M] = X[N,K] @ W[K,M] (+bias[M]) (+add[N,M]) ----------------
// MFMA f16 inputs, fp32 accumulate. 128x128 tile, BK=64, 256 threads = 2x2 waves,
// each wave owns a 64x64 sub-tile = 4x4 fragments of 16x16x32.
// A staged in LDS as f16 [128 rows][64 k], XOR-swizzled (byte ^= (row&7)<<4).
// B read directly from pre-transposed f16 Wt[M][K] (tiny, L2-resident).
__global__ __launch_bounds__(256) void gemm_k(
        const float* __restrict__ X, const _Float16* __restrict__ Wt,
        const float* __restrict__ bias, const float* __restrict__ add,
        float* __restrict__ Y, int N, int K, int M) {
    __shared__ _Float16 As[128 * 64];   // 16 KB
    char* asb = (char*)As;
    const int tid = threadIdx.x;
    const int lane = tid & 63;
    const int wid = tid >> 6;
    const int wr = wid >> 1, wc = wid & 1;   // wave grid 2x2
    const int bm = blockIdx.y * 128;
    const int bn = blockIdx.x * 128;
    const int l15 = lane & 15, lk = lane >> 4;

    floatx4 acc[4][4] = {};   // [row-frag][col-frag]

    for (int k0 = 0; k0 < K; k0 += 64) {
        #pragma unroll
        for (int i = 0; i < 8; ++i) {
            int f = tid + i * 256;         // float4 slot 0..2047
            int r = f >> 4, kq = f & 15;   // row, k-quad
            int gr = bm + r;
            float4 v = make_float4(0.f, 0.f, 0.f, 0.f);
            if (gr < N) v = *(const float4*)&X[(long)gr * K + k0 + kq * 4];
            half4 hv = { (_Float16)v.x, (_Float16)v.y, (_Float16)v.z, (_Float16)v.w };
            int byte = (r * 128 + kq * 8) ^ ((r & 7) << 4);
            *(half4*)(asb + byte) = hv;
        }
        half8 bf[2][4];
        #pragma unroll
        for (int kk = 0; kk < 2; ++kk)
            #pragma unroll
            for (int ct = 0; ct < 4; ++ct) {
                int col = bn + wc * 64 + ct * 16 + l15;
                bf[kk][ct] = *(const half8*)&Wt[(long)col * K + k0 + kk * 32 + lk * 8];
            }
        __syncthreads();
        #pragma unroll
        for (int kk = 0; kk < 2; ++kk) {
            half8 af[4];
            #pragma unroll
            for (int rt = 0; rt < 4; ++rt) {
                int row = wr * 64 + rt * 16 + l15;
                int byte = (row * 128 + (kk * 32 + lk * 8) * 2) ^ ((row & 7) << 4);
                af[rt] = *(const half8*)(asb + byte);
            }
            #pragma unroll
            for (int rt = 0; rt < 4; ++rt)
                #pragma unroll
                for (int ct = 0; ct < 4; ++ct)
                    acc[rt][ct] = __builtin_amdgcn_mfma_f32_16x16x32_f16(
                        af[rt], bf[kk][ct], acc[rt][ct], 0, 0, 0);
        }
        __syncthreads();
    }
    #pragma unroll
    for (int ct = 0; ct < 4; ++ct) {
        int col = bn + wc * 64 + ct * 16 + l15;
        float bv = bias ? bias[col] : 0.f;
        #pragma unroll
        for (int rt = 0; rt < 4; ++rt) {
            #pragma unroll
            for (int r = 0; r < 4; ++r) {
                int row = bm + wr * 64 + rt * 16 + lk * 4 + r;
                if (row < N) {
                    float v = acc[rt][ct][r] + bv;
                    long off = (long)row * M + col;
                    if (add) v += add[off];
                    Y[off] = v;
                }
            }
        }
    }
}

// ---------------- edge kernel: f = lrelu(FNi[src]+FNj[dst]+FEb[e>>sh]); ef_out = sum_h f; logits = f . attn ----------------
__global__ __launch_bounds__(256) void edge_k(
        const float* __restrict__ FNi, const float* __restrict__ FNj,
        const float* __restrict__ FEb, const float* __restrict__ attn,
        const int* __restrict__ src, const int* __restrict__ dst,
        int E, int out_e, int fe_shift,
        float* __restrict__ ef_out, float* __restrict__ logits) {
    int e = blockIdx.x * 4 + (threadIdx.x >> 6);
    int lane = threadIdx.x & 63;
    if (e >= E) return;
    int s = src[e], d = dst[e];
    long fi = (long)s * (2 * out_e);
    long fj = (long)d * (2 * out_e);
    long fe = (long)(e >> fe_shift) * (2 * out_e);
    float l0 = 0.f, l1 = 0.f;
    for (int c = lane; c < out_e; c += 64) {
        float f0 = FNi[fi + c] + FNj[fj + c] + FEb[fe + c];
        f0 = f0 > 0.f ? f0 : 0.01f * f0;
        float f1 = FNi[fi + out_e + c] + FNj[fj + out_e + c] + FEb[fe + out_e + c];
        f1 = f1 > 0.f ? f1 : 0.01f * f1;
        l0 += f0 * attn[c];
        l1 += f1 * attn[out_e + c];
        ef_out[(long)e * out_e + c] = f0 + f1;
    }
    #pragma unroll
    for (int off = 32; off > 0; off >>= 1) {
        l0 += __shfl_down(l0, off);
        l1 += __shfl_down(l1, off);
    }
    if (lane == 0) { logits[2 * e] = l0; logits[2 * e + 1] = l1; }
}

// ---------------- fused softmax-aggregate over CSR: one wave per dst node ----------------
// out[n][c] = sum_e softmax_w(e) * Hn[src[e]][head][c], heads folded (Hn stride 256, out 128)
__global__ __launch_bounds__(256) void aggregate_k(
        const float* __restrict__ Hn, const float* __restrict__ logits,
        const int* __restrict__ off, const int* __restrict__ eidx,
        const int* __restrict__ src, int N, float* __restrict__ out) {
    int n = blockIdx.x * 4 + (threadIdx.x >> 6);
    int lane = threadIdx.x & 63;
    if (n >= N) return;
    int i0 = off[n], i1 = off[n + 1];
    float m0 = -3.0e38f, m1 = -3.0e38f;
    for (int i = i0; i < i1; ++i) {
        int e = eidx[i];
        m0 = fmaxf(m0, logits[2 * e]);
        m1 = fmaxf(m1, logits[2 * e + 1]);
    }
    float s0 = 0.f, s1 = 0.f;
    for (int i = i0; i < i1; ++i) {
        int e = eidx[i];
        s0 += __expf(logits[2 * e]     - m0);
        s1 += __expf(logits[2 * e + 1] - m1);
    }
    float r0 = 1.f / s0, r1 = 1.f / s1;
    float acc0 = 0.f, acc1 = 0.f;
    for (int i = i0; i < i1; ++i) {
        int e = eidx[i];
        float w0 = __expf(logits[2 * e]     - m0) * r0;
        float w1 = __expf(logits[2 * e + 1] - m1) * r1;
        const float* h = Hn + (long)src[e] * 256;
        acc0 += w0 * h[lane]      + w1 * h[128 + lane];
        acc1 += w0 * h[64 + lane] + w1 * h[192 + lane];
    }
    float* o = out + (long)n * 128;
    o[lane]      = acc0;
    o[64 + lane] = acc1;
}

extern "C" void kernel_launch(void* const* d_in, const int* in_sizes, int n_in,
                              void* d_out, int out_size, void* d_ws, size_t ws_size,
                              hipStream_t stream) {
    const float* node_feats   = (const float*)d_in[0];
    const float* edge_feats   = (const float*)d_in[1];
    const float* node_path_in = (const float*)d_in[2];
    const float* edge_path_in = (const float*)d_in[3];
    const float* lin1_b = (const float*)d_in[33];
    const int* src0 = (const int*)d_in[34];
    const int* dst0 = (const int*)d_in[35];
    const int* src1 = (const int*)d_in[36];
    const int* dst1 = (const int*)d_in[37];

    float* out  = (float*)d_out;
    float* seg0 = out;              // nf        [50000,128]
    float* seg1 = out + 6400000;    // ef2       [200000,128]
    float* seg2 = out + 32000000;   // node_path [100000,128]
    float* seg3 = out + 44800000;   // edge_path [400000,64]

    float* ws     = (float*)d_ws;
    float* FNi    = ws;                   // 12.8M floats
    float* FNj    = FNi + 12800000;       // 12.8M
    float* Hn     = FNj + 12800000;       // 25.6M
    float* FE     = Hn  + 25600000;       // 51.2M
    float* EF     = FE  + 51200000;       // 25.6M
    float* np2    = EF  + 25600000;       // 12.8M
    float* logits = np2 + 12800000;       // 0.8M
    _Float16* WT  = (_Float16*)(logits + 800000);   // 442368 f16
    int* ib    = (int*)(WT + 442368);
    int* off0  = ib;                 // 50001
    int* eidx0 = off0 + 50001;       // 200000
    int* off1  = eidx0 + 200000;     // 100001
    int* eidx1 = off1 + 100001;      // 400000
    int* deg0  = eidx1 + 400000;     // 50000
    int* cur0  = deg0 + 50000;       // 50000
    int* deg1  = cur0 + 50000;       // 100000
    int* cur1  = deg1 + 100000;      // 100000
    int* bsum0 = cur1 + 100000;      // 196
    int* bsum1 = bsum0 + 196;        // 391
    // total ~572 MB of ws (harness allocation is ~1.13 GB per fillBuffer profile)

    const int nb0 = (CN0 + 255) / 256;   // 196
    const int nb1 = (CN1 + 255) / 256;   // 391

    // ---- f16 transposed weights ----
    static const int wi_din[17]  = {4,5,6,7, 11,12,13,14, 18,19,20,21, 25,26,27,28, 32};
    static const int wi_K[17]    = {128,128,128,128, 128,128,64,128, 128,128,64,128, 128,128,128,128, 256};
    static const int wi_M[17]    = {256,256,256,256, 128,128,128,256, 128,128,128,256, 256,256,256,256, 128};
    _Float16* wt[17];
    {
        _Float16* p = WT;
        for (int i = 0; i < 17; ++i) { wt[i] = p; p += (size_t)wi_K[i] * wi_M[i]; }
    }
    {
        WtArgs a;
        for (int i = 0; i < 17; ++i) {
            a.d[i].W = (const float*)d_in[wi_din[i]];
            a.d[i].T = wt[i];
            a.d[i].KM = wi_K[i] * wi_M[i];
            a.d[i].mshift = (wi_M[i] == 256) ? 8 : 7;
            a.d[i].K = wi_K[i];
        }
        wcvt_k<<<dim3(4, 17), 256, 0, stream>>>(a);
    }

    // ---- CSR build for both graphs (dst-sorted incoming-edge lists) ----
    fill_k<<<(300000 + 255) / 256, 256, 0, stream>>>((float*)deg0, 0.f, 300000); // deg0,cur0,deg1,cur1
    hist2_k<<<(CE1 + 255) / 256, 256, 0, stream>>>(dst0, dst1, deg0, deg1);
    scanA_k<<<nb0, 256, 0, stream>>>(deg0, CN0, off0, bsum0);
    scanA_k<<<nb1, 256, 0, stream>>>(deg1, CN1, off1, bsum1);
    scanB_k<<<2, 256, 0, stream>>>(bsum0, nb0, bsum1, nb1);
    scanC_k<<<nb0, 256, 0, stream>>>(off0, bsum0, CN0, CE0);
    scanC_k<<<nb1, 256, 0, stream>>>(off1, bsum1, CN1, CE1);
    csrfill2_k<<<(CE1 + 255) / 256, 256, 0, stream>>>(dst0, off0, cur0, eidx0,
                                                      dst1, off1, cur1, eidx1);

    auto gemm = [&](const float* X, const _Float16* Wt, const float* b, const float* add,
                    float* Y, int N, int K, int M) {
        dim3 g(M / 128, (N + 127) / 128);
        gemm_k<<<g, 256, 0, stream>>>(X, Wt, b, add, Y, N, K, M);
    };
    // One EGAT layer. base = index of <pre>_ni in d_in; wb = index into wt[].
    auto egat = [&](const float* nfeats, int N, int in_n,
                    const float* efeats, int fij_rows, int in_e,
                    int out_e, int fe_shift, int base, int wb,
                    const int* src, const int* dst, int E,
                    const int* off, const int* eidx,
                    float* ef_out, float* h_out) {
        const float* bnode = (const float*)d_in[base + 4];
        const float* attn  = (const float*)d_in[base + 5];
        const float* bias  = (const float*)d_in[base + 6];
        gemm(nfeats, wt[wb + 0], nullptr, nullptr, FNi, N, in_n, 2 * out_e);
        gemm(nfeats, wt[wb + 1], nullptr, nullptr, FNj, N, in_n, 2 * out_e);
        gemm(nfeats, wt[wb + 3], bnode,   nullptr, Hn,  N, in_n, 256);
        gemm(efeats, wt[wb + 2], bias,    nullptr, FE,  fij_rows, in_e, 2 * out_e);
        edge_k<<<(E + 3) / 4, 256, 0, stream>>>(FNi, FNj, FE, attn, src, dst,
                                                E, out_e, fe_shift, ef_out, logits);
        aggregate_k<<<(N + 3) / 4, 256, 0, stream>>>(Hn, logits, off, eidx, src, N, h_out);
    };

    // ---- Stage 1: EGAT on atom graph ----  nf1 -> seg0, ef1 -> seg1
    egat(node_feats, CN0, 128, edge_feats, CE0, 128, 128, 0, 4, 0,
         src0, dst0, CE0, off0, eidx0, seg1, seg0);

    // ---- Lift: np1 = [ef1 as [100000,256]] @ lin1_W + lin1_b + node_path_in -> seg2
    gemm(seg1, wt[16], lin1_b, node_path_in, seg2, CN1, 256, 128);

    // ---- Stage 2a: path graph ----  ef -> EF (ws), h -> np2 (ws)
    egat(seg2, CN1, 128, edge_path_in, CE1, 64, 64, 0, 11, 4,
         src1, dst1, CE1, off1, eidx1, EF, np2);

    // ---- Stage 2b: path graph ----  ef -> seg3 (final edge_path), h -> seg2 (final node_path)
    egat(np2, CN1, 128, EF, CE1, 64, 64, 0, 18, 8,
         src1, dst1, CE1, off1, eidx1, seg3, seg2);

    // ---- Stage 3: atom graph ----
    // efeats = repeat(node_path,2): fij GEMM on 100000 unique rows, edge kernel indexes e>>1.
    // nfeats = nf1 (seg0); GEMMs read seg0 before aggregate overwrites it (same-stream order).
    egat(seg0, CN0, 128, seg2, CN1, 128, 128, 1, 25, 12,
         src0, dst0, CE0, off0, eidx0, seg1, seg0);
}

// Round 4
// 2483.134 us; speedup vs baseline: 1.2711x; 1.0696x over previous
//
#include <hip/hip_runtime.h>

#define CN0 50000
#define CE0 200000
#define CN1 100000
#define CE1 400000

typedef __attribute__((ext_vector_type(8))) _Float16 half8;
typedef __attribute__((ext_vector_type(4))) _Float16 half4;
typedef __attribute__((ext_vector_type(4))) float floatx4;

// ---------------- fill ----------------
__global__ void fill_k(float* __restrict__ p, float v, int n) {
    int i = blockIdx.x * 256 + threadIdx.x;
    if (i < n) p[i] = v;
}

// ---------------- weight convert+transpose: T[m*K+k] = (f16)W[k*M+m] ----------------
struct WtDesc { const float* W; _Float16* T; int KM; int mshift; int K; };
struct WtArgs { WtDesc d[17]; };

__global__ __launch_bounds__(256) void wcvt_k(WtArgs a) {
    WtDesc w = a.d[blockIdx.y];
    const int M1 = (1 << w.mshift) - 1;
    for (int i = blockIdx.x * 256 + threadIdx.x; i < w.KM; i += 256 * gridDim.x) {
        int k = i >> w.mshift, m = i & M1;
        w.T[(long)m * w.K + k] = (_Float16)w.W[i];
    }
}

// ---------------- CSR build: histogram -> block scan -> carry scan -> apply -> fill ----------------
__global__ void hist2_k(const int* __restrict__ dst0, const int* __restrict__ dst1,
                        int* __restrict__ deg0, int* __restrict__ deg1) {
    int i = blockIdx.x * 256 + threadIdx.x;
    if (i < CE0) atomicAdd(&deg0[dst0[i]], 1);
    if (i < CE1) atomicAdd(&deg1[dst1[i]], 1);
}

// per-block exclusive scan of deg -> off (block-local), block totals -> bsum
__global__ __launch_bounds__(256) void scanA_k(const int* __restrict__ deg, int N,
                                               int* __restrict__ off, int* __restrict__ bsum) {
    __shared__ int s[256];
    int t = threadIdx.x, i = blockIdx.x * 256 + t;
    int v = (i < N) ? deg[i] : 0;
    s[t] = v; __syncthreads();
    #pragma unroll
    for (int d = 1; d < 256; d <<= 1) {
        int x = (t >= d) ? s[t - d] : 0;
        __syncthreads(); s[t] += x; __syncthreads();
    }
    if (i < N) off[i] = s[t] - v;
    if (t == 255) bsum[blockIdx.x] = s[255];
}

// exclusive scan of bsum arrays (block 0 -> graph0, block 1 -> graph1)
__global__ __launch_bounds__(256) void scanB_k(int* __restrict__ bsum0, int nb0,
                                               int* __restrict__ bsum1, int nb1) {
    int* bs = blockIdx.x ? bsum1 : bsum0;
    int nb  = blockIdx.x ? nb1 : nb0;
    __shared__ int s[256];
    __shared__ int tot, carry;
    int t = threadIdx.x;
    if (t == 0) carry = 0;
    __syncthreads();
    for (int base = 0; base < nb; base += 256) {
        int i = base + t;
        int v = (i < nb) ? bs[i] : 0;
        s[t] = v; __syncthreads();
        #pragma unroll
        for (int d = 1; d < 256; d <<= 1) {
            int x = (t >= d) ? s[t - d] : 0;
            __syncthreads(); s[t] += x; __syncthreads();
        }
        if (i < nb) bs[i] = s[t] - v + carry;
        if (t == 255) tot = s[255];
        __syncthreads();
        if (t == 0) carry += tot;
        __syncthreads();
    }
}

__global__ void scanC_k(int* __restrict__ off, const int* __restrict__ bsum, int N, int E) {
    int i = blockIdx.x * 256 + threadIdx.x;
    if (i < N) off[i] += bsum[i >> 8];
    if (i == 0) off[N] = E;
}

// fill CSR: csrc[slot] = src[e] (gathered source ids, CSR order) and pos[e] = slot (inverse perm)
__global__ void csrfill2_k(const int* __restrict__ src0, const int* __restrict__ dst0,
                           const int* __restrict__ off0, int* __restrict__ cur0,
                           int* __restrict__ csrc0, int* __restrict__ pos0,
                           const int* __restrict__ src1, const int* __restrict__ dst1,
                           const int* __restrict__ off1, int* __restrict__ cur1,
                           int* __restrict__ csrc1, int* __restrict__ pos1) {
    int i = blockIdx.x * 256 + threadIdx.x;
    if (i < CE0) {
        int d = dst0[i];
        int slot = off0[d] + atomicAdd(&cur0[d], 1);
        csrc0[slot] = src0[i];
        pos0[i] = slot;
    }
    if (i < CE1) {
        int d = dst1[i];
        int slot = off1[d] + atomicAdd(&cur1[d], 1);
        csrc1[slot] = src1[i];
        pos1[i] = slot;
    }
}

// ---------------- GEMM: Y[N,M] = X[N,K] @ W[K,M] (+bias[M]) (+add[N,M]) ----------------
// MFMA f16 inputs, fp32 accumulate. 128x128 tile, BK=64, 256 threads = 2x2 waves,
// each wave owns a 64x64 sub-tile = 4x4 fragments of 16x16x32.
// A staged in LDS as f16 [128 rows][64 k], XOR-swizzled (byte ^= (row&7)<<4).
// B read directly from pre-transposed f16 Wt[M][K] (tiny, L2-resident).
__global__ __launch_bounds__(256) void gemm_k(
        const float* __restrict__ X, const _Float16* __restrict__ Wt,
        const float* __restrict__ bias, const float* __restrict__ add,
        float* __restrict__ Y, int N, int K, int M) {
    __shared__ _Float16 As[128 * 64];   // 16 KB
    char* asb = (char*)As;
    const int tid = threadIdx.x;
    const int lane = tid & 63;
    const int wid = tid >> 6;
    const int wr = wid >> 1, wc = wid & 1;   // wave grid 2x2
    const int bm = blockIdx.y * 128;
    const int bn = blockIdx.x * 128;
    const int l15 = lane & 15, lk = lane >> 4;

    floatx4 acc[4][4] = {};   // [row-frag][col-frag]

    for (int k0 = 0; k0 < K; k0 += 64) {
        #pragma unroll
        for (int i = 0; i < 8; ++i) {
            int f = tid + i * 256;         // float4 slot 0..2047
            int r = f >> 4, kq = f & 15;   // row, k-quad
            int gr = bm + r;
            float4 v = make_float4(0.f, 0.f, 0.f, 0.f);
            if (gr < N) v = *(const float4*)&X[(long)gr * K + k0 + kq * 4];
            half4 hv = { (_Float16)v.x, (_Float16)v.y, (_Float16)v.z, (_Float16)v.w };
            int byte = (r * 128 + kq * 8) ^ ((r & 7) << 4);
            *(half4*)(asb + byte) = hv;
        }
        half8 bf[2][4];
        #pragma unroll
        for (int kk = 0; kk < 2; ++kk)
            #pragma unroll
            for (int ct = 0; ct < 4; ++ct) {
                int col = bn + wc * 64 + ct * 16 + l15;
                bf[kk][ct] = *(const half8*)&Wt[(long)col * K + k0 + kk * 32 + lk * 8];
            }
        __syncthreads();
        #pragma unroll
        for (int kk = 0; kk < 2; ++kk) {
            half8 af[4];
            #pragma unroll
            for (int rt = 0; rt < 4; ++rt) {
                int row = wr * 64 + rt * 16 + l15;
                int byte = (row * 128 + (kk * 32 + lk * 8) * 2) ^ ((row & 7) << 4);
                af[rt] = *(const half8*)(asb + byte);
            }
            #pragma unroll
            for (int rt = 0; rt < 4; ++rt)
                #pragma unroll
                for (int ct = 0; ct < 4; ++ct)
                    acc[rt][ct] = __builtin_amdgcn_mfma_f32_16x16x32_f16(
                        af[rt], bf[kk][ct], acc[rt][ct], 0, 0, 0);
        }
        __syncthreads();
    }
    #pragma unroll
    for (int ct = 0; ct < 4; ++ct) {
        int col = bn + wc * 64 + ct * 16 + l15;
        float bv = bias ? bias[col] : 0.f;
        #pragma unroll
        for (int rt = 0; rt < 4; ++rt) {
            #pragma unroll
            for (int r = 0; r < 4; ++r) {
                int row = bm + wr * 64 + rt * 16 + lk * 4 + r;
                if (row < N) {
                    float v = acc[rt][ct][r] + bv;
                    long off = (long)row * M + col;
                    if (add) v += add[off];
                    Y[off] = v;
                }
            }
        }
    }
}

// ---------------- edge kernel: f = lrelu(FNi[src]+FNj[dst]+FEb[e>>sh]); ef_out = sum_h f; logits (CSR order) = f . attn ----------------
__global__ __launch_bounds__(256) void edge_k(
        const float* __restrict__ FNi, const float* __restrict__ FNj,
        const float* __restrict__ FEb, const float* __restrict__ attn,
        const int* __restrict__ src, const int* __restrict__ dst,
        const int* __restrict__ pos,
        int E, int out_e, int fe_shift,
        float* __restrict__ ef_out, float* __restrict__ clog) {
    int e = blockIdx.x * 4 + (threadIdx.x >> 6);
    int lane = threadIdx.x & 63;
    if (e >= E) return;
    int s = src[e], d = dst[e];
    long fi = (long)s * (2 * out_e);
    long fj = (long)d * (2 * out_e);
    long fe = (long)(e >> fe_shift) * (2 * out_e);
    float l0 = 0.f, l1 = 0.f;
    for (int c = lane; c < out_e; c += 64) {
        float f0 = FNi[fi + c] + FNj[fj + c] + FEb[fe + c];
        f0 = f0 > 0.f ? f0 : 0.01f * f0;
        float f1 = FNi[fi + out_e + c] + FNj[fj + out_e + c] + FEb[fe + out_e + c];
        f1 = f1 > 0.f ? f1 : 0.01f * f1;
        l0 += f0 * attn[c];
        l1 += f1 * attn[out_e + c];
        ef_out[(long)e * out_e + c] = f0 + f1;
    }
    #pragma unroll
    for (int off = 32; off > 0; off >>= 1) {
        l0 += __shfl_down(l0, off);
        l1 += __shfl_down(l1, off);
    }
    if (lane == 0) {
        int p = pos[e];
        float2 lv = { l0, l1 };
        *(float2*)&clog[2 * p] = lv;
    }
}

// ---------------- fused softmax-aggregate over CSR: one wave per dst node ----------------
// clog is in CSR order; csrc[i] = src id of CSR slot i. Two passes: max, then accumulate
// unnormalized per-head (accA=sum e0'*h0, accB=sum e1'*h1, s=sum e'), normalize once.
__global__ __launch_bounds__(256) void aggregate_k(
        const float* __restrict__ Hn, const float* __restrict__ clog,
        const int* __restrict__ off, const int* __restrict__ csrc,
        int N, float* __restrict__ out) {
    int n = blockIdx.x * 4 + (threadIdx.x >> 6);
    int lane = threadIdx.x & 63;
    if (n >= N) return;
    int i0 = off[n], i1 = off[n + 1];
    float m0 = -3.0e38f, m1 = -3.0e38f;
    for (int i = i0; i < i1; ++i) {
        float2 l = *(const float2*)&clog[2 * i];
        m0 = fmaxf(m0, l.x);
        m1 = fmaxf(m1, l.y);
    }
    float s0 = 0.f, s1 = 0.f;
    float2 accA = make_float2(0.f, 0.f), accB = make_float2(0.f, 0.f);
    for (int i = i0; i < i1; ++i) {
        float2 l = *(const float2*)&clog[2 * i];
        float w0 = __expf(l.x - m0);
        float w1 = __expf(l.y - m1);
        s0 += w0; s1 += w1;
        const float* h = Hn + (long)csrc[i] * 256;
        float2 h0 = *(const float2*)&h[2 * lane];
        float2 h1 = *(const float2*)&h[128 + 2 * lane];
        accA.x += w0 * h0.x; accA.y += w0 * h0.y;
        accB.x += w1 * h1.x; accB.y += w1 * h1.y;
    }
    float r0 = 1.f / s0, r1 = 1.f / s1;
    float2 o;
    o.x = accA.x * r0 + accB.x * r1;
    o.y = accA.y * r0 + accB.y * r1;
    *(float2*)&out[(long)n * 128 + 2 * lane] = o;
}

extern "C" void kernel_launch(void* const* d_in, const int* in_sizes, int n_in,
                              void* d_out, int out_size, void* d_ws, size_t ws_size,
                              hipStream_t stream) {
    const float* node_feats   = (const float*)d_in[0];
    const float* edge_feats   = (const float*)d_in[1];
    const float* node_path_in = (const float*)d_in[2];
    const float* edge_path_in = (const float*)d_in[3];
    const float* lin1_b = (const float*)d_in[33];
    const int* src0 = (const int*)d_in[34];
    const int* dst0 = (const int*)d_in[35];
    const int* src1 = (const int*)d_in[36];
    const int* dst1 = (const int*)d_in[37];

    float* out  = (float*)d_out;
    float* seg0 = out;              // nf        [50000,128]
    float* seg1 = out + 6400000;    // ef2       [200000,128]
    float* seg2 = out + 32000000;   // node_path [100000,128]
    float* seg3 = out + 44800000;   // edge_path [400000,64]

    float* ws     = (float*)d_ws;
    float* FNi    = ws;                   // 12.8M floats
    float* FNj    = FNi + 12800000;       // 12.8M
    float* Hn     = FNj + 12800000;       // 25.6M
    float* FE     = Hn  + 25600000;       // 51.2M
    float* EF     = FE  + 51200000;       // 25.6M
    float* np2    = EF  + 25600000;       // 12.8M
    float* logits = np2 + 12800000;       // 0.8M (CSR-ordered clog)
    _Float16* WT  = (_Float16*)(logits + 800000);   // 442368 f16
    int* ib    = (int*)(WT + 442368);
    int* off0  = ib;                 // 50001
    int* csrc0 = off0 + 50001;       // 200000
    int* off1  = csrc0 + 200000;     // 100001
    int* csrc1 = off1 + 100001;      // 400000
    int* pos0  = csrc1 + 400000;     // 200000
    int* pos1  = pos0 + 200000;      // 400000
    int* deg0  = pos1 + 400000;      // 50000   (deg0,cur0,deg1,cur1 contiguous: one fill)
    int* cur0  = deg0 + 50000;       // 50000
    int* deg1  = cur0 + 50000;       // 100000
    int* cur1  = deg1 + 100000;      // 100000
    int* bsum0 = cur1 + 100000;      // 196
    int* bsum1 = bsum0 + 196;        // 391

    const int nb0 = (CN0 + 255) / 256;   // 196
    const int nb1 = (CN1 + 255) / 256;   // 391

    // ---- f16 transposed weights ----
    static const int wi_din[17]  = {4,5,6,7, 11,12,13,14, 18,19,20,21, 25,26,27,28, 32};
    static const int wi_K[17]    = {128,128,128,128, 128,128,64,128, 128,128,64,128, 128,128,128,128, 256};
    static const int wi_M[17]    = {256,256,256,256, 128,128,128,256, 128,128,128,256, 256,256,256,256, 128};
    _Float16* wt[17];
    {
        _Float16* p = WT;
        for (int i = 0; i < 17; ++i) { wt[i] = p; p += (size_t)wi_K[i] * wi_M[i]; }
    }
    {
        WtArgs a;
        for (int i = 0; i < 17; ++i) {
            a.d[i].W = (const float*)d_in[wi_din[i]];
            a.d[i].T = wt[i];
            a.d[i].KM = wi_K[i] * wi_M[i];
            a.d[i].mshift = (wi_M[i] == 256) ? 8 : 7;
            a.d[i].K = wi_K[i];
        }
        wcvt_k<<<dim3(4, 17), 256, 0, stream>>>(a);
    }

    // ---- CSR build for both graphs (dst-sorted; csrc = gathered src ids, pos = inverse perm) ----
    fill_k<<<(300000 + 255) / 256, 256, 0, stream>>>((float*)deg0, 0.f, 300000); // deg0,cur0,deg1,cur1
    hist2_k<<<(CE1 + 255) / 256, 256, 0, stream>>>(dst0, dst1, deg0, deg1);
    scanA_k<<<nb0, 256, 0, stream>>>(deg0, CN0, off0, bsum0);
    scanA_k<<<nb1, 256, 0, stream>>>(deg1, CN1, off1, bsum1);
    scanB_k<<<2, 256, 0, stream>>>(bsum0, nb0, bsum1, nb1);
    scanC_k<<<nb0, 256, 0, stream>>>(off0, bsum0, CN0, CE0);
    scanC_k<<<nb1, 256, 0, stream>>>(off1, bsum1, CN1, CE1);
    csrfill2_k<<<(CE1 + 255) / 256, 256, 0, stream>>>(src0, dst0, off0, cur0, csrc0, pos0,
                                                      src1, dst1, off1, cur1, csrc1, pos1);

    auto gemm = [&](const float* X, const _Float16* Wt, const float* b, const float* add,
                    float* Y, int N, int K, int M) {
        dim3 g(M / 128, (N + 127) / 128);
        gemm_k<<<g, 256, 0, stream>>>(X, Wt, b, add, Y, N, K, M);
    };
    // One EGAT layer. base = index of <pre>_ni in d_in; wb = index into wt[].
    auto egat = [&](const float* nfeats, int N, int in_n,
                    const float* efeats, int fij_rows, int in_e,
                    int out_e, int fe_shift, int base, int wb,
                    const int* src, const int* dst, int E,
                    const int* off, const int* csrc, const int* pos,
                    float* ef_out, float* h_out) {
        const float* bnode = (const float*)d_in[base + 4];
        const float* attn  = (const float*)d_in[base + 5];
        const float* bias  = (const float*)d_in[base + 6];
        gemm(nfeats, wt[wb + 0], nullptr, nullptr, FNi, N, in_n, 2 * out_e);
        gemm(nfeats, wt[wb + 1], nullptr, nullptr, FNj, N, in_n, 2 * out_e);
        gemm(nfeats, wt[wb + 3], bnode,   nullptr, Hn,  N, in_n, 256);
        gemm(efeats, wt[wb + 2], bias,    nullptr, FE,  fij_rows, in_e, 2 * out_e);
        edge_k<<<(E + 3) / 4, 256, 0, stream>>>(FNi, FNj, FE, attn, src, dst, pos,
                                                E, out_e, fe_shift, ef_out, logits);
        aggregate_k<<<(N + 3) / 4, 256, 0, stream>>>(Hn, logits, off, csrc, N, h_out);
    };

    // ---- Stage 1: EGAT on atom graph ----  nf1 -> seg0, ef1 -> seg1
    egat(node_feats, CN0, 128, edge_feats, CE0, 128, 128, 0, 4, 0,
         src0, dst0, CE0, off0, csrc0, pos0, seg1, seg0);

    // ---- Lift: np1 = [ef1 as [100000,256]] @ lin1_W + lin1_b + node_path_in -> seg2
    gemm(seg1, wt[16], lin1_b, node_path_in, seg2, CN1, 256, 128);

    // ---- Stage 2a: path graph ----  ef -> EF (ws), h -> np2 (ws)
    egat(seg2, CN1, 128, edge_path_in, CE1, 64, 64, 0, 11, 4,
         src1, dst1, CE1, off1, csrc1, pos1, EF, np2);

    // ---- Stage 2b: path graph ----  ef -> seg3 (final edge_path), h -> seg2 (final node_path)
    egat(np2, CN1, 128, EF, CE1, 64, 64, 0, 18, 8,
         src1, dst1, CE1, off1, csrc1, pos1, seg3, seg2);

    // ---- Stage 3: atom graph ----
    // efeats = repeat(node_path,2): fij GEMM on 100000 unique rows, edge kernel indexes e>>1.
    // nfeats = nf1 (seg0); GEMMs read seg0 before aggregate overwrites it (same-stream order).
    egat(seg0, CN0, 128, seg2, CN1, 128, 128, 1, 25, 12,
         src0, dst0, CE0, off0, csrc0, pos0, seg1, seg0);
}

// Round 5
// 2181.199 us; speedup vs baseline: 1.4471x; 1.1384x over previous
//
#include <hip/hip_runtime.h>

#define CN0 50000
#define CE0 200000
#define CN1 100000
#define CE1 400000

typedef __attribute__((ext_vector_type(8))) _Float16 half8;
typedef __attribute__((ext_vector_type(4))) _Float16 half4;
typedef __attribute__((ext_vector_type(2))) _Float16 half2h;
typedef __attribute__((ext_vector_type(4))) float floatx4;

// ---------------- fill ----------------
__global__ void fill_k(float* __restrict__ p, float v, int n) {
    int i = blockIdx.x * 256 + threadIdx.x;
    if (i < n) p[i] = v;
}

// ---------------- weight convert+transpose(+head-interleave): ----------------
// T[m'*K+k] = (f16)W[k*M+m], m' = head-interleaved (2c+h) when oesh>0, else m.
struct WtDesc { const float* W; _Float16* T; int KM; int mshift; int K; int oesh; };
struct WtArgs { WtDesc d[17]; };

__global__ __launch_bounds__(256) void wcvt_k(WtArgs a) {
    WtDesc w = a.d[blockIdx.y];
    const int M1 = (1 << w.mshift) - 1;
    for (int i = blockIdx.x * 256 + threadIdx.x; i < w.KM; i += 256 * gridDim.x) {
        int k = i >> w.mshift, m = i & M1;
        int m2 = w.oesh ? (((m & ((1 << w.oesh) - 1)) << 1) | (m >> w.oesh)) : m;
        w.T[(long)m2 * w.K + k] = (_Float16)w.W[i];
    }
}

// ---------------- edge-bias head-interleave permute: o[2c+h] = b[h*oe+c] ----------------
struct BpDesc { const float* b; float* o; int oe; };
struct BpArgs { BpDesc d[4]; };

__global__ __launch_bounds__(256) void bperm_k(BpArgs a) {
    BpDesc d = a.d[blockIdx.x];
    int m = threadIdx.x;
    if (m < 2 * d.oe) {
        int h = (m >= d.oe) ? 1 : 0;
        int c = m - h * d.oe;
        d.o[2 * c + h] = d.b[m];
    }
}

// ---------------- CSR build ----------------
__global__ void hist2_k(const int* __restrict__ dst0, const int* __restrict__ dst1,
                        int* __restrict__ deg0, int* __restrict__ deg1) {
    int i = blockIdx.x * 256 + threadIdx.x;
    if (i < CE0) atomicAdd(&deg0[dst0[i]], 1);
    if (i < CE1) atomicAdd(&deg1[dst1[i]], 1);
}

__global__ __launch_bounds__(256) void scanA_k(const int* __restrict__ deg, int N,
                                               int* __restrict__ off, int* __restrict__ bsum) {
    __shared__ int s[256];
    int t = threadIdx.x, i = blockIdx.x * 256 + t;
    int v = (i < N) ? deg[i] : 0;
    s[t] = v; __syncthreads();
    #pragma unroll
    for (int d = 1; d < 256; d <<= 1) {
        int x = (t >= d) ? s[t - d] : 0;
        __syncthreads(); s[t] += x; __syncthreads();
    }
    if (i < N) off[i] = s[t] - v;
    if (t == 255) bsum[blockIdx.x] = s[255];
}

__global__ __launch_bounds__(256) void scanB_k(int* __restrict__ bsum0, int nb0,
                                               int* __restrict__ bsum1, int nb1) {
    int* bs = blockIdx.x ? bsum1 : bsum0;
    int nb  = blockIdx.x ? nb1 : nb0;
    __shared__ int s[256];
    __shared__ int tot, carry;
    int t = threadIdx.x;
    if (t == 0) carry = 0;
    __syncthreads();
    for (int base = 0; base < nb; base += 256) {
        int i = base + t;
        int v = (i < nb) ? bs[i] : 0;
        s[t] = v; __syncthreads();
        #pragma unroll
        for (int d = 1; d < 256; d <<= 1) {
            int x = (t >= d) ? s[t - d] : 0;
            __syncthreads(); s[t] += x; __syncthreads();
        }
        if (i < nb) bs[i] = s[t] - v + carry;
        if (t == 255) tot = s[255];
        __syncthreads();
        if (t == 0) carry += tot;
        __syncthreads();
    }
}

__global__ void scanC_k(int* __restrict__ off, const int* __restrict__ bsum, int N, int E) {
    int i = blockIdx.x * 256 + threadIdx.x;
    if (i < N) off[i] += bsum[i >> 8];
    if (i == 0) off[N] = E;
}

__global__ void csrfill2_k(const int* __restrict__ src0, const int* __restrict__ dst0,
                           const int* __restrict__ off0, int* __restrict__ cur0,
                           int* __restrict__ csrc0, int* __restrict__ pos0,
                           const int* __restrict__ src1, const int* __restrict__ dst1,
                           const int* __restrict__ off1, int* __restrict__ cur1,
                           int* __restrict__ csrc1, int* __restrict__ pos1) {
    int i = blockIdx.x * 256 + threadIdx.x;
    if (i < CE0) {
        int d = dst0[i];
        int slot = off0[d] + atomicAdd(&cur0[d], 1);
        csrc0[slot] = src0[i];
        pos0[i] = slot;
    }
    if (i < CE1) {
        int d = dst1[i];
        int slot = off1[d] + atomicAdd(&cur1[d], 1);
        csrc1[slot] = src1[i];
        pos1[i] = slot;
    }
}

// ---------------- GEMM: Y[N,M] = X[N,K] @ Wt^T (+bias[M]) (+add[N,M]), TO = float | _Float16 ----------------
// MFMA f16, fp32 acc. 128x128 tile, BK=64, 2x2 waves, 4x4 frags of 16x16x32 each.
// A in LDS f16, XOR-swizzled (byte ^= (row&7)<<4). B direct from f16 Wt[M][K] (L2-resident).
template <typename TO>
__global__ __launch_bounds__(256) void gemm_t(
        const float* __restrict__ X, const _Float16* __restrict__ Wt,
        const float* __restrict__ bias, const float* __restrict__ add,
        TO* __restrict__ Y, int N, int K, int M) {
    __shared__ _Float16 As[128 * 64];   // 16 KB
    char* asb = (char*)As;
    const int tid = threadIdx.x;
    const int lane = tid & 63;
    const int wid = tid >> 6;
    const int wr = wid >> 1, wc = wid & 1;
    const int bm = blockIdx.y * 128;
    const int bn = blockIdx.x * 128;
    const int l15 = lane & 15, lk = lane >> 4;

    floatx4 acc[4][4] = {};

    for (int k0 = 0; k0 < K; k0 += 64) {
        #pragma unroll
        for (int i = 0; i < 8; ++i) {
            int f = tid + i * 256;
            int r = f >> 4, kq = f & 15;
            int gr = bm + r;
            float4 v = make_float4(0.f, 0.f, 0.f, 0.f);
            if (gr < N) v = *(const float4*)&X[(long)gr * K + k0 + kq * 4];
            half4 hv = { (_Float16)v.x, (_Float16)v.y, (_Float16)v.z, (_Float16)v.w };
            int byte = (r * 128 + kq * 8) ^ ((r & 7) << 4);
            *(half4*)(asb + byte) = hv;
        }
        half8 bf[2][4];
        #pragma unroll
        for (int kk = 0; kk < 2; ++kk)
            #pragma unroll
            for (int ct = 0; ct < 4; ++ct) {
                int col = bn + wc * 64 + ct * 16 + l15;
                bf[kk][ct] = *(const half8*)&Wt[(long)col * K + k0 + kk * 32 + lk * 8];
            }
        __syncthreads();
        #pragma unroll
        for (int kk = 0; kk < 2; ++kk) {
            half8 af[4];
            #pragma unroll
            for (int rt = 0; rt < 4; ++rt) {
                int row = wr * 64 + rt * 16 + l15;
                int byte = (row * 128 + (kk * 32 + lk * 8) * 2) ^ ((row & 7) << 4);
                af[rt] = *(const half8*)(asb + byte);
            }
            #pragma unroll
            for (int rt = 0; rt < 4; ++rt)
                #pragma unroll
                for (int ct = 0; ct < 4; ++ct)
                    acc[rt][ct] = __builtin_amdgcn_mfma_f32_16x16x32_f16(
                        af[rt], bf[kk][ct], acc[rt][ct], 0, 0, 0);
        }
        __syncthreads();
    }
    #pragma unroll
    for (int ct = 0; ct < 4; ++ct) {
        int col = bn + wc * 64 + ct * 16 + l15;
        float bv = bias ? bias[col] : 0.f;
        #pragma unroll
        for (int rt = 0; rt < 4; ++rt) {
            #pragma unroll
            for (int r = 0; r < 4; ++r) {
                int row = bm + wr * 64 + rt * 16 + lk * 4 + r;
                if (row < N) {
                    float v = acc[rt][ct][r] + bv;
                    long o = (long)row * M + col;
                    if (add) v += add[o];
                    Y[o] = (TO)v;
                }
            }
        }
    }
}

// ---------------- edge kernel (f16 in, head-interleaved FN/FE) ----------------
// FN row: [2*oe interleaved ni][2*oe interleaved nj][256 Hn], stride nstride.
// f = lrelu(FNi[src]+FNj[dst]+FE[e>>sh]); ef_out = f0+f1 (fp32); clog[pos[e]] = f.attn
__global__ __launch_bounds__(256) void edge_k(
        const _Float16* __restrict__ FN, const _Float16* __restrict__ FE,
        const float* __restrict__ attn,
        const int* __restrict__ src, const int* __restrict__ dst,
        const int* __restrict__ pos,
        int E, int oe, int fe_shift, int nstride,
        float* __restrict__ ef_out, float* __restrict__ clog) {
    int e = blockIdx.x * 4 + (threadIdx.x >> 6);
    int lane = threadIdx.x & 63;
    if (e >= E) return;
    int s = src[e], d = dst[e];
    long fi = (long)s * nstride;
    long fj = (long)d * nstride + 2 * oe;
    long fe = (long)(e >> fe_shift) * (2 * oe);
    float l0 = 0.f, l1 = 0.f;
    for (int c = lane; c < oe; c += 64) {
        half2h a = *(const half2h*)&FN[fi + 2 * c];
        half2h b = *(const half2h*)&FN[fj + 2 * c];
        half2h g = *(const half2h*)&FE[fe + 2 * c];
        float f0 = (float)a.x + (float)b.x + (float)g.x;
        f0 = f0 > 0.f ? f0 : 0.01f * f0;
        float f1 = (float)a.y + (float)b.y + (float)g.y;
        f1 = f1 > 0.f ? f1 : 0.01f * f1;
        l0 += f0 * attn[c];
        l1 += f1 * attn[oe + c];
        ef_out[(long)e * oe + c] = f0 + f1;
    }
    #pragma unroll
    for (int off = 32; off > 0; off >>= 1) {
        l0 += __shfl_down(l0, off);
        l1 += __shfl_down(l1, off);
    }
    if (lane == 0) {
        int p = pos[e];
        float2 lv = { l0, l1 };
        *(float2*)&clog[2 * p] = lv;
    }
}

// ---------------- fused softmax-aggregate over CSR (f16 Hn), bnode folded via sum(a)=1 ----------------
__global__ __launch_bounds__(256) void aggregate_k(
        const _Float16* __restrict__ Hn, int stride, const float* __restrict__ bnode,
        const float* __restrict__ clog, const int* __restrict__ off,
        const int* __restrict__ csrc, int N, float* __restrict__ out) {
    int n = blockIdx.x * 4 + (threadIdx.x >> 6);
    int lane = threadIdx.x & 63;
    if (n >= N) return;
    int i0 = off[n], i1 = off[n + 1];
    float m0 = -3.0e38f, m1 = -3.0e38f;
    for (int i = i0; i < i1; ++i) {
        float2 l = *(const float2*)&clog[2 * i];
        m0 = fmaxf(m0, l.x);
        m1 = fmaxf(m1, l.y);
    }
    float s0 = 0.f, s1 = 0.f;
    float2 accA = make_float2(0.f, 0.f), accB = make_float2(0.f, 0.f);
    for (int i = i0; i < i1; ++i) {
        float2 l = *(const float2*)&clog[2 * i];
        float w0 = __expf(l.x - m0);
        float w1 = __expf(l.y - m1);
        s0 += w0; s1 += w1;
        const _Float16* h = Hn + (long)csrc[i] * stride;
        half2h h0 = *(const half2h*)&h[2 * lane];
        half2h h1 = *(const half2h*)&h[128 + 2 * lane];
        accA.x += w0 * (float)h0.x; accA.y += w0 * (float)h0.y;
        accB.x += w1 * (float)h1.x; accB.y += w1 * (float)h1.y;
    }
    float r0 = 1.f / s0, r1 = 1.f / s1;
    float2 o;
    o.x = accA.x * r0 + accB.x * r1 + bnode[2 * lane]     + bnode[128 + 2 * lane];
    o.y = accA.y * r0 + accB.y * r1 + bnode[2 * lane + 1] + bnode[128 + 2 * lane + 1];
    *(float2*)&out[(long)n * 128 + 2 * lane] = o;
}

extern "C" void kernel_launch(void* const* d_in, const int* in_sizes, int n_in,
                              void* d_out, int out_size, void* d_ws, size_t ws_size,
                              hipStream_t stream) {
    const float* node_feats   = (const float*)d_in[0];
    const float* edge_feats   = (const float*)d_in[1];
    const float* node_path_in = (const float*)d_in[2];
    const float* edge_path_in = (const float*)d_in[3];
    const float* lin1_b = (const float*)d_in[33];
    const int* src0 = (const int*)d_in[34];
    const int* dst0 = (const int*)d_in[35];
    const int* src1 = (const int*)d_in[36];
    const int* dst1 = (const int*)d_in[37];

    float* out  = (float*)d_out;
    float* seg0 = out;              // nf        [50000,128]
    float* seg1 = out + 6400000;    // ef2       [200000,128]
    float* seg2 = out + 32000000;   // node_path [100000,128]
    float* seg3 = out + 44800000;   // edge_path [400000,64]

    float* ws      = (float*)d_ws;
    _Float16* FN   = (_Float16*)ws;            // 51.2M f16 (node-side combined: FNi|FNj|Hn)
    _Float16* FE16 = FN + 51200000;            // 51.2M f16
    float* EF   = (float*)(FE16 + 51200000);   // 25.6M f32 (stage2a edge out)
    float* np2  = EF + 25600000;               // 12.8M
    float* clog = np2 + 12800000;              // 0.8M (CSR-ordered logits)
    float* biasI = clog + 800000;              // 1024 (interleaved edge biases)
    _Float16* WT = (_Float16*)(biasI + 1024);  // 442368 f16
    int* ib    = (int*)(WT + 442368);
    int* off0  = ib;                 // 50001
    int* csrc0 = off0 + 50001;       // 200000
    int* off1  = csrc0 + 200000;     // 100001
    int* csrc1 = off1 + 100001;      // 400000
    int* pos0  = csrc1 + 400000;     // 200000
    int* pos1  = pos0 + 200000;      // 400000
    int* deg0  = pos1 + 400000;      // 50000  (deg0,cur0,deg1,cur1 contiguous: one fill)
    int* cur0  = deg0 + 50000;       // 50000
    int* deg1  = cur0 + 50000;       // 100000
    int* cur1  = deg1 + 100000;      // 100000
    int* bsum0 = cur1 + 100000;      // 196
    int* bsum1 = bsum0 + 196;        // 391

    const int nb0 = (CN0 + 255) / 256;   // 196
    const int nb1 = (CN1 + 255) / 256;   // 391

    // ---- f16 weights: arena order per layer = [ni|nj|node] (combined), then fij; lin1 last ----
    // entry order: ni,nj,node,fij per layer; head-interleave (oesh>0) on ni/nj/fij only.
    static const int wi_din[17]  = {4,5,7,6, 11,12,14,13, 18,19,21,20, 25,26,28,27, 32};
    static const int wi_M[17]    = {256,256,256,256, 128,128,256,128, 128,128,256,128, 256,256,256,256, 128};
    static const int wi_K[17]    = {128,128,128,128, 128,128,128,64, 128,128,128,64, 128,128,128,128, 256};
    static const int wi_oesh[17] = {7,7,0,7, 6,6,0,6, 6,6,0,6, 7,7,0,7, 0};
    _Float16* wtp[17];
    {
        _Float16* p = WT;
        for (int i = 0; i < 17; ++i) { wtp[i] = p; p += (size_t)wi_M[i] * wi_K[i]; }
    }
    _Float16* nodeW[4] = { wtp[0], wtp[4], wtp[8],  wtp[12] };
    _Float16* fijW[4]  = { wtp[3], wtp[7], wtp[11], wtp[15] };
    _Float16* lin1t    = wtp[16];
    {
        WtArgs a;
        for (int i = 0; i < 17; ++i) {
            a.d[i].W = (const float*)d_in[wi_din[i]];
            a.d[i].T = wtp[i];
            a.d[i].KM = wi_M[i] * wi_K[i];
            a.d[i].mshift = (wi_M[i] == 256) ? 8 : 7;
            a.d[i].K = wi_K[i];
            a.d[i].oesh = wi_oesh[i];
        }
        wcvt_k<<<dim3(4, 17), 256, 0, stream>>>(a);
    }
    // interleaved edge biases: L1 @0 (256), L2a @256 (128), L2b @384 (128), L3 @512 (256)
    float* biasL[4] = { biasI, biasI + 256, biasI + 384, biasI + 512 };
    {
        BpArgs b;
        static const int bdin[4] = {10, 17, 24, 31};
        static const int boe[4]  = {128, 64, 64, 128};
        for (int i = 0; i < 4; ++i) {
            b.d[i].b = (const float*)d_in[bdin[i]];
            b.d[i].o = biasL[i];
            b.d[i].oe = boe[i];
        }
        bperm_k<<<4, 256, 0, stream>>>(b);
    }

    // ---- CSR build for both graphs ----
    fill_k<<<(300000 + 255) / 256, 256, 0, stream>>>((float*)deg0, 0.f, 300000);
    hist2_k<<<(CE1 + 255) / 256, 256, 0, stream>>>(dst0, dst1, deg0, deg1);
    scanA_k<<<nb0, 256, 0, stream>>>(deg0, CN0, off0, bsum0);
    scanA_k<<<nb1, 256, 0, stream>>>(deg1, CN1, off1, bsum1);
    scanB_k<<<2, 256, 0, stream>>>(bsum0, nb0, bsum1, nb1);
    scanC_k<<<nb0, 256, 0, stream>>>(off0, bsum0, CN0, CE0);
    scanC_k<<<nb1, 256, 0, stream>>>(off1, bsum1, CN1, CE1);
    csrfill2_k<<<(CE1 + 255) / 256, 256, 0, stream>>>(src0, dst0, off0, cur0, csrc0, pos0,
                                                      src1, dst1, off1, cur1, csrc1, pos1);

    // One EGAT layer. L = layer idx (weights/bias arrays); base = d_in idx of <pre>_ni.
    auto egat = [&](const float* nfeats, int N, int in_n,
                    const float* efeats, int fij_rows, int in_e,
                    int oe, int fe_shift, int base, int L,
                    const int* src, const int* dst, int E,
                    const int* off, const int* csrc, const int* pos,
                    float* ef_out, float* h_out) {
        const float* bnode = (const float*)d_in[base + 4];
        const float* attn  = (const float*)d_in[base + 5];
        const int Mtot = 4 * oe + 256;
        {   // combined node-side GEMM: [FNi|FNj|Hn], f16 out, no bias (bnode folded in aggregate)
            dim3 g(Mtot / 128, (N + 127) / 128);
            gemm_t<_Float16><<<g, 256, 0, stream>>>(nfeats, nodeW[L], nullptr, nullptr,
                                                    FN, N, in_n, Mtot);
        }
        {   // edge-side GEMM: f16 out, interleaved bias
            dim3 g((2 * oe) / 128, (fij_rows + 127) / 128);
            gemm_t<_Float16><<<g, 256, 0, stream>>>(efeats, fijW[L], biasL[L], nullptr,
                                                    FE16, fij_rows, in_e, 2 * oe);
        }
        edge_k<<<(E + 3) / 4, 256, 0, stream>>>(FN, FE16, attn, src, dst, pos,
                                                E, oe, fe_shift, Mtot, ef_out, clog);
        aggregate_k<<<(N + 3) / 4, 256, 0, stream>>>(FN + 4 * oe, Mtot, bnode,
                                                     clog, off, csrc, N, h_out);
    };

    // ---- Stage 1: atom graph ----  nf1 -> seg0, ef1 -> seg1
    egat(node_feats, CN0, 128, edge_feats, CE0, 128, 128, 0, 4, 0,
         src0, dst0, CE0, off0, csrc0, pos0, seg1, seg0);

    // ---- Lift: np1 = [ef1 as [100000,256]] @ lin1_W + lin1_b + node_path_in -> seg2
    {
        dim3 g(1, (CN1 + 127) / 128);
        gemm_t<float><<<g, 256, 0, stream>>>(seg1, lin1t, lin1_b, node_path_in,
                                             seg2, CN1, 256, 128);
    }

    // ---- Stage 2a: path graph ----  ef -> EF (ws), h -> np2 (ws)
    egat(seg2, CN1, 128, edge_path_in, CE1, 64, 64, 0, 11, 1,
         src1, dst1, CE1, off1, csrc1, pos1, EF, np2);

    // ---- Stage 2b: path graph ----  ef -> seg3 (final edge_path), h -> seg2 (final node_path)
    egat(np2, CN1, 128, EF, CE1, 64, 64, 0, 18, 2,
         src1, dst1, CE1, off1, csrc1, pos1, seg3, seg2);

    // ---- Stage 3: atom graph ----
    // efeats = repeat(node_path,2): fij GEMM on 100000 unique rows, edge kernel indexes e>>1.
    // nfeats = nf1 (seg0); node GEMM reads seg0 before aggregate overwrites it (same stream).
    egat(seg0, CN0, 128, seg2, CN1, 128, 128, 1, 25, 3,
         src0, dst0, CE0, off0, csrc0, pos0, seg1, seg0);
}